// Round 12
// baseline (612.572 us; speedup 1.0000x reference)
//
#include <hip/hip_runtime.h>
#include <hip/hip_bf16.h>

#define M_DIM 4096
#define N_DIM 8192
#define K_DIM 8192
#define CAP   768          // bin capacity per W row (mean 488, sigma 22)
#define OVF_CAP 4096
#define FILL_STRIDE 32     // one counter per 128-B cacheline (r12 fix)

using bf16x8 = __attribute__((ext_vector_type(8))) short;
using f32x4  = __attribute__((ext_vector_type(4))) float;

static __device__ __forceinline__ unsigned short f32_to_bf16_rne(float f) {
    unsigned u = __float_as_uint(f);
    unsigned rounding = 0x7FFFu + ((u >> 16) & 1u);
    u += rounding;
    return (unsigned short)(u >> 16);
}

// ---------------- fused pass 1: cvt x -> bf16  ||  bin items by row -------
// Roles interleaved by bid parity (even = cast, odd = bin) so both
// populations are co-resident from the first dispatch wave.  Binning is
// 4 items/thread (int4/float4 loads, independent atomic chains).
// r12 fix: fill counters padded to ONE PER 128-B CACHELINE.  Dense packing
// (32 counters/line, 256 lines) forced ~15.6K serialized same-line atomics
// per line (~60 us floor + cross-XCD line ping-pong); padding spreads the
// 4M ops over 8192 lines (~488/line, ~2 us).  bins[row][pos] =
// (col<<16)|bf16(val).  Overflow (>=13 sigma, ~impossible) -> list merged
// by row_accum.
__global__ void cvt_reorder_kernel(const float4* __restrict__ xsrc,
                                   ushort4* __restrict__ xdst, int xn4,
                                   const float* __restrict__ vals,
                                   const int* __restrict__ rows,
                                   const int* __restrict__ cols,
                                   unsigned* __restrict__ bins,
                                   unsigned* __restrict__ fill,
                                   unsigned* __restrict__ ovf_cnt,
                                   uint2* __restrict__ ovf, int n) {
    const int half = (int)gridDim.x >> 1;
    const int bi   = blockIdx.x >> 1;
    if ((blockIdx.x & 1) == 0) {
        // ---- cast role: grid-stride over x ----
        int i = bi * blockDim.x + threadIdx.x;
        int stride = half * blockDim.x;
        for (; i < xn4; i += stride) {
            float4 v = xsrc[i];
            ushort4 o;
            o.x = f32_to_bf16_rne(v.x);
            o.y = f32_to_bf16_rne(v.y);
            o.z = f32_to_bf16_rne(v.z);
            o.w = f32_to_bf16_rne(v.w);
            xdst[i] = o;
        }
        return;
    }
    // ---- binning role: 4 items/thread ----
    int i = (bi * blockDim.x + threadIdx.x) * 4;
    if (i >= n) return;
    const int m = n - i;               // >= 1; full int4 load safe (i % 4 == 0)
    int4   r4 = *(const int4*)(rows + i);
    int4   c4 = *(const int4*)(cols + i);
    float4 v4 = *(const float4*)(vals + i);
    const int   ra[4] = {r4.x, r4.y, r4.z, r4.w};
    const int   ca[4] = {c4.x, c4.y, c4.z, c4.w};
    const float va[4] = {v4.x, v4.y, v4.z, v4.w};
    #pragma unroll
    for (int j = 0; j < 4; ++j) {
        if (j >= m) break;
        int r = ra[j], c = ca[j];
        unsigned h = f32_to_bf16_rne(va[j]);
        unsigned pos = atomicAdd(&fill[(size_t)r * FILL_STRIDE], 1u);
        if (pos < CAP) {
            bins[(size_t)r * CAP + pos] = ((unsigned)c << 16) | h;
        } else {
            unsigned o = atomicAdd(ovf_cnt, 1u);
            if (o < OVF_CAP)
                ovf[o] = make_uint2((unsigned)r * K_DIM + (unsigned)c, h);
        }
    }
}

// ---------------- pass 2: per-row accumulate + write full bf16 row --------
// One block per W row: f32 LDS rowbuf (32 KB), LDS atomics for ~488 items,
// merge any overflow entries for this row (f32, pre-rounding), then one
// coalesced 16 KB row write.  Replaces the W-zero pass, the global atomic
// scatter, AND a separate ovf_apply launch.
__global__ __launch_bounds__(256) void row_accum_kernel(
        const unsigned* __restrict__ bins,
        const unsigned* __restrict__ fill,
        const unsigned* __restrict__ ovf_cnt,
        const uint2* __restrict__ ovf,
        unsigned short* __restrict__ W) {
    __shared__ float rowbuf[K_DIM];    // 32 KB
    const int row = blockIdx.x;
    const int tid = threadIdx.x;
    float4* rb4 = (float4*)rowbuf;
    #pragma unroll
    for (int i = 0; i < K_DIM / 4 / 256; ++i)
        rb4[i * 256 + tid] = make_float4(0.f, 0.f, 0.f, 0.f);
    __syncthreads();
    int n = (int)fill[(size_t)row * FILL_STRIDE];
    if (n > CAP) n = CAP;
    const unsigned* seg = bins + (size_t)row * CAP;
    for (int i = tid; i < n; i += 256) {
        unsigned u = seg[i];
        atomicAdd(&rowbuf[u >> 16], __uint_as_float((u & 0xffffu) << 16));
    }
    unsigned ocnt = *ovf_cnt;          // ~always 0
    if (ocnt) {
        if (ocnt > OVF_CAP) ocnt = OVF_CAP;
        for (unsigned i = tid; i < ocnt; i += 256) {
            uint2 e = ovf[i];
            if ((int)(e.x >> 13) == row)   // K_DIM = 8192 = 2^13
                atomicAdd(&rowbuf[e.x & (K_DIM - 1)],
                          __uint_as_float((e.y & 0xffffu) << 16));
        }
    }
    __syncthreads();
    unsigned* Wrow = (unsigned*)(W + (size_t)row * K_DIM);  // 4096 dwords
    #pragma unroll
    for (int i = 0; i < K_DIM / 2 / 256; ++i) {
        int j = i * 256 + tid;
        unsigned pa = f32_to_bf16_rne(rowbuf[2 * j]);
        unsigned pb = f32_to_bf16_rne(rowbuf[2 * j + 1]);
        Wrow[j] = pa | (pb << 16);
    }
}

// ---------------- zero d_out fallback (ws too small diagnostic) ----------------
__global__ void zero_out_kernel(float* __restrict__ p, int n) {
    int i = blockIdx.x * blockDim.x + threadIdx.x;
    int stride = gridDim.x * blockDim.x;
    for (; i < n; i += stride) p[i] = 0.f;
}

// ---------------- bf16 NT GEMM, 256x256 8-phase (T2+T3+T4+T5) ----------------
// EXACT r6 schedule (measured 425-440 us, ~1280 TF, MfmaUtil 56-57,
// conflicts 0).  Structural variants all regressed and are closed:
//   r4/r5 32x32x16 frags   -> intrinsic 4 cyc/b128 read penalty (485 us)
//   r7 full fragment hoist -> defeated per-phase counted waits (643 us)
//   r9 (ksub,mh) phases    -> added lgkm serialization points (460 us)
// C[M][N] = A[M][K] * B[N][K]^T.  BM=BN=256, BK=64, 8 waves (2M x 4N),
// per-wave output 128x64 (acc[8][4] f32x4).  LDS 128 KiB double-buffered.
// Per K-tile: 4 phases {ds_read subtile | stage 1 half-tile | barrier |
// lgkmcnt(0) | setprio(1) 16 MFMA setprio(0) | (boundary vmcnt) | barrier};
// vmcnt(4) only at tile boundaries.  Staging liveness:
//   q0: A(t+1) h0 -> db^1   q1: A(t+1) h1 -> db^1
//   q2: B(t+2) h0 -> db     q3: B(t+2) h1 -> db   (B[db] dead after q0)
// LDS swizzle (T2, rule #21): slot (row,c) holds global k-chunk c^(row&7);
// staging pre-swizzles the global source, reads apply the same involution.
__global__ __launch_bounds__(512, 2) void gemm_bt(const ushort* __restrict__ A,
                                                  const ushort* __restrict__ B,
                                                  float* __restrict__ C) {
    constexpr int BK = 64;
    constexpr int NT = K_DIM / BK;     // 128 K-tiles
    __shared__ ushort lds[65536];      // 128 KiB

    const int nbn = N_DIM / 256;       // 32
    const int bm = blockIdx.x / nbn;
    const int bn = blockIdx.x % nbn;
    const int brow = bm * 256, bcol = bn * 256;

    const int t    = threadIdx.x;
    const int lane = t & 63;
    const int wid  = t >> 6;           // 0..7
    const int wm   = wid >> 2;         // 0..1 (M)
    const int wn   = wid & 3;          // 0..3 (N)
    const int lrow = lane & 15;
    const int ghi  = lane >> 4;        // 0..3

    const int c0 = (0 + ghi) ^ (lrow & 7);   // ksub 0
    const int c1 = (4 + ghi) ^ (lrow & 7);   // ksub 1

    f32x4  acc[8][4] = {};
    bf16x8 bfr[4][2];                  // B frags, live across one tile

    auto stage_half = [&](int db, int op, int half, int ktile) {
        const ushort* G = (op == 0) ? A : B;
        const int rbase = ((op == 0) ? brow : bcol) + half * 128;
        #pragma unroll
        for (int i = 0; i < 2; ++i) {
            int fl  = i * 512 + t;                 // 0..1023
            int row = fl >> 3;
            int cc  = (fl & 7) ^ (row & 7);
            const ushort* src = G + (size_t)(rbase + row) * K_DIM + ktile * BK + cc * 8;
            __builtin_amdgcn_global_load_lds(
                (const __attribute__((address_space(1))) void*)src,
                (__attribute__((address_space(3))) void*)
                    (&lds[db * 32768 + op * 16384 + half * 8192 + fl * 8]),
                16, 0, 0);
        }
    };

    auto tile_body = [&](int tt, int db, bool stgA, bool stgB, int vm) {
        const ushort* Ah = &lds[db * 32768 + wm * 8192];
        const ushort* Bh = &lds[db * 32768 + 16384 + (wn >> 1) * 8192 + (wn & 1) * 4096];
        const ushort* a0 = Ah + lrow * 64 + c0 * 8;
        const ushort* a1 = Ah + lrow * 64 + c1 * 8;
        const ushort* b0 = Bh + lrow * 64 + c0 * 8;
        const ushort* b1 = Bh + lrow * 64 + c1 * 8;
        #pragma unroll
        for (int q = 0; q < 4; ++q) {
            bf16x8 af[2][2];
            if (q == 0) {
                #pragma unroll
                for (int n = 0; n < 4; ++n) {
                    bfr[n][0] = *(const bf16x8*)(b0 + n * 1024);
                    bfr[n][1] = *(const bf16x8*)(b1 + n * 1024);
                }
            }
            #pragma unroll
            for (int j = 0; j < 2; ++j) {
                af[j][0] = *(const bf16x8*)(a0 + (2 * q + j) * 1024);
                af[j][1] = *(const bf16x8*)(a1 + (2 * q + j) * 1024);
            }
            if (q == 0 && stgA) stage_half(db ^ 1, 0, 0, tt + 1);
            if (q == 1 && stgA) stage_half(db ^ 1, 0, 1, tt + 1);
            if (q == 2 && stgB) stage_half(db,     1, 0, tt + 2);
            if (q == 3 && stgB) stage_half(db,     1, 1, tt + 2);
            __builtin_amdgcn_s_barrier();
            asm volatile("s_waitcnt lgkmcnt(0)" ::: "memory");
            __builtin_amdgcn_s_setprio(1);
            #pragma unroll
            for (int j = 0; j < 2; ++j)
                #pragma unroll
                for (int n = 0; n < 4; ++n) {
                    acc[2 * q + j][n] = __builtin_amdgcn_mfma_f32_16x16x32_bf16(
                        af[j][0], bfr[n][0], acc[2 * q + j][n], 0, 0, 0);
                    acc[2 * q + j][n] = __builtin_amdgcn_mfma_f32_16x16x32_bf16(
                        af[j][1], bfr[n][1], acc[2 * q + j][n], 0, 0, 0);
                }
            __builtin_amdgcn_s_setprio(0);
            if (q == 3) {
                if (vm == 4) asm volatile("s_waitcnt vmcnt(4)" ::: "memory");
                else         asm volatile("s_waitcnt vmcnt(0)" ::: "memory");
            }
            __builtin_amdgcn_s_barrier();
        }
    };

    // ---- prologue: tile 0 fully + B(1); drain to 4 (B(1) stays in flight) ----
    stage_half(0, 0, 0, 0);
    stage_half(0, 0, 1, 0);
    stage_half(0, 1, 0, 0);
    stage_half(0, 1, 1, 0);
    stage_half(1, 1, 0, 1);
    stage_half(1, 1, 1, 1);
    asm volatile("s_waitcnt vmcnt(4)" ::: "memory");
    __builtin_amdgcn_s_barrier();

    for (int tt = 0; tt < NT - 2; tt += 2) {
        tile_body(tt,     0, true, true, 4);
        tile_body(tt + 1, 1, true, true, 4);
    }
    tile_body(NT - 2, 0, true,  false, 0);
    tile_body(NT - 1, 1, false, false, 0);

    // ---- epilogue: C/D layout col=lane&15, row=(lane>>4)*4+r ----
    const int crow0 = brow + wm * 128;
    const int ccol0 = bcol + wn * 64;
    #pragma unroll
    for (int m = 0; m < 8; ++m) {
        #pragma unroll
        for (int n = 0; n < 4; ++n) {
            int col   = ccol0 + n * 16 + lrow;
            int rbase = crow0 + m * 16 + (lane >> 4) * 4;
            #pragma unroll
            for (int r = 0; r < 4; ++r)
                C[(size_t)(rbase + r) * N_DIM + col] = acc[m][n][r];
        }
    }
}

extern "C" void kernel_launch(void* const* d_in, const int* in_sizes, int n_in,
                              void* d_out, int out_size, void* d_ws, size_t ws_size,
                              hipStream_t stream) {
    const float* x    = (const float*)d_in[0];
    const float* vals = (const float*)d_in[1];
    const int* rows   = (const int*)d_in[2];
    const int* cols   = (const int*)d_in[3];
    float* out        = (float*)d_out;
    const int n_items = in_sizes[1];

    const size_t W_BF16_BYTES = (size_t)N_DIM * K_DIM * 2;              // 128 MiB
    const size_t X_BF16_BYTES = (size_t)M_DIM * K_DIM * 2;              //  64 MiB
    const size_t BINS_BYTES   = (size_t)N_DIM * CAP * 4;                //  24 MiB
    const size_t FILL_BYTES   = (size_t)N_DIM * FILL_STRIDE * 4;        //   1 MiB
    const size_t OVF_BYTES    = 16 + (size_t)OVF_CAP * 8;
    const size_t NEEDED = W_BF16_BYTES + X_BF16_BYTES + BINS_BYTES
                        + FILL_BYTES + OVF_BYTES;

    if (ws_size < NEEDED) {
        // Diagnostic fallback: clean absmax=126 failure signals ws too small.
        zero_out_kernel<<<2048, 256, 0, stream>>>(out, out_size);
        return;
    }

    char* ws = (char*)d_ws;
    unsigned short* Wb = (unsigned short*)ws;
    ushort*   Xb      = (ushort*)(ws + W_BF16_BYTES);
    unsigned* bins    = (unsigned*)(ws + W_BF16_BYTES + X_BF16_BYTES);
    unsigned* fill    = (unsigned*)(ws + W_BF16_BYTES + X_BF16_BYTES + BINS_BYTES);
    unsigned* ovf_cnt = fill + N_DIM * FILL_STRIDE;
    uint2*    ovf     = (uint2*)(ovf_cnt + 4);

    // 1) zero fill counters + ovf_cnt (stream memset: graph-capturable)
    hipMemsetAsync(fill, 0, FILL_BYTES + 16, stream);
    // 2) fused: cast x to bf16 (even bids) || bin items 4/thread (odd bids)
    const int reorder_blocks = (n_items / 4 + 255) / 256;   // 3907
    cvt_reorder_kernel<<<2 * reorder_blocks, 256, 0, stream>>>(
        (const float4*)x, (ushort4*)Xb, (M_DIM * K_DIM) / 4,
        vals, rows, cols, bins, fill, ovf_cnt, ovf, n_items);
    // 3) per-row accumulate in f32 LDS + merge overflow + write bf16 W
    row_accum_kernel<<<N_DIM, 256, 0, stream>>>(bins, fill, ovf_cnt, ovf, Wb);
    // 4) GEMM: out = Xb (M x K) * Wb (N x K)^T
    gemm_bt<<<(M_DIM / 256) * (N_DIM / 256), 512, 0, stream>>>(
        Xb, (const ushort*)Wb, out);
}

// Round 13
// 579.611 us; speedup vs baseline: 1.0569x; 1.0569x over previous
//
#include <hip/hip_runtime.h>
#include <hip/hip_bf16.h>

#define M_DIM 4096
#define N_DIM 8192
#define K_DIM 8192
#define CAP   768          // bin capacity per W row (mean 488, sigma 22)
#define OVF_CAP 4096

using bf16x8 = __attribute__((ext_vector_type(8))) short;
using f32x4  = __attribute__((ext_vector_type(4))) float;

static __device__ __forceinline__ unsigned short f32_to_bf16_rne(float f) {
    unsigned u = __float_as_uint(f);
    unsigned rounding = 0x7FFFu + ((u >> 16) & 1u);
    u += rounding;
    return (unsigned short)(u >> 16);
}

// ---------------- fused pass 1: cvt x -> bf16  ||  bin items by row -------
// Roles interleaved by bid parity (even = cast, odd = bin) so both
// populations are co-resident from the first dispatch wave.  Binning is
// 4 items/thread (int4/float4 loads, independent atomic chains).
// fill[] is DENSE (r12's one-counter-per-cacheline padding cost +32 us:
// 256 hot lines across L2 atomic banks were already parallel enough; the
// padding traded a hot 32 KB set for 8192 cold line-allocates).
// bins[row][pos] = (col<<16)|bf16(val); pos via device-scope atomicAdd on
// fill[row].  Overflow (>=13 sigma, ~impossible) -> list merged by row_accum.
__global__ void cvt_reorder_kernel(const float4* __restrict__ xsrc,
                                   ushort4* __restrict__ xdst, int xn4,
                                   const float* __restrict__ vals,
                                   const int* __restrict__ rows,
                                   const int* __restrict__ cols,
                                   unsigned* __restrict__ bins,
                                   unsigned* __restrict__ fill,
                                   unsigned* __restrict__ ovf_cnt,
                                   uint2* __restrict__ ovf, int n) {
    const int half = (int)gridDim.x >> 1;
    const int bi   = blockIdx.x >> 1;
    if ((blockIdx.x & 1) == 0) {
        // ---- cast role: grid-stride over x ----
        int i = bi * blockDim.x + threadIdx.x;
        int stride = half * blockDim.x;
        for (; i < xn4; i += stride) {
            float4 v = xsrc[i];
            ushort4 o;
            o.x = f32_to_bf16_rne(v.x);
            o.y = f32_to_bf16_rne(v.y);
            o.z = f32_to_bf16_rne(v.z);
            o.w = f32_to_bf16_rne(v.w);
            xdst[i] = o;
        }
        return;
    }
    // ---- binning role: 4 items/thread ----
    int i = (bi * blockDim.x + threadIdx.x) * 4;
    if (i >= n) return;
    const int m = n - i;               // >= 1; full int4 load safe (i % 4 == 0)
    int4   r4 = *(const int4*)(rows + i);
    int4   c4 = *(const int4*)(cols + i);
    float4 v4 = *(const float4*)(vals + i);
    const int   ra[4] = {r4.x, r4.y, r4.z, r4.w};
    const int   ca[4] = {c4.x, c4.y, c4.z, c4.w};
    const float va[4] = {v4.x, v4.y, v4.z, v4.w};
    #pragma unroll
    for (int j = 0; j < 4; ++j) {
        if (j >= m) break;
        int r = ra[j], c = ca[j];
        unsigned h = f32_to_bf16_rne(va[j]);
        unsigned pos = atomicAdd(&fill[r], 1u);
        if (pos < CAP) {
            bins[(size_t)r * CAP + pos] = ((unsigned)c << 16) | h;
        } else {
            unsigned o = atomicAdd(ovf_cnt, 1u);
            if (o < OVF_CAP)
                ovf[o] = make_uint2((unsigned)r * K_DIM + (unsigned)c, h);
        }
    }
}

// ---------------- pass 2: per-row accumulate + write full bf16 row --------
// One block per W row: f32 LDS rowbuf (32 KB), LDS atomics for ~488 items,
// merge any overflow entries for this row (f32, pre-rounding), then one
// coalesced 16 KB row write.  Replaces the W-zero pass, the global atomic
// scatter, AND a separate ovf_apply launch.
__global__ __launch_bounds__(256) void row_accum_kernel(
        const unsigned* __restrict__ bins,
        const unsigned* __restrict__ fill,
        const unsigned* __restrict__ ovf_cnt,
        const uint2* __restrict__ ovf,
        unsigned short* __restrict__ W) {
    __shared__ float rowbuf[K_DIM];    // 32 KB
    const int row = blockIdx.x;
    const int tid = threadIdx.x;
    float4* rb4 = (float4*)rowbuf;
    #pragma unroll
    for (int i = 0; i < K_DIM / 4 / 256; ++i)
        rb4[i * 256 + tid] = make_float4(0.f, 0.f, 0.f, 0.f);
    __syncthreads();
    int n = (int)fill[row];
    if (n > CAP) n = CAP;
    const unsigned* seg = bins + (size_t)row * CAP;
    for (int i = tid; i < n; i += 256) {
        unsigned u = seg[i];
        atomicAdd(&rowbuf[u >> 16], __uint_as_float((u & 0xffffu) << 16));
    }
    unsigned ocnt = *ovf_cnt;          // ~always 0
    if (ocnt) {
        if (ocnt > OVF_CAP) ocnt = OVF_CAP;
        for (unsigned i = tid; i < ocnt; i += 256) {
            uint2 e = ovf[i];
            if ((int)(e.x >> 13) == row)   // K_DIM = 8192 = 2^13
                atomicAdd(&rowbuf[e.x & (K_DIM - 1)],
                          __uint_as_float((e.y & 0xffffu) << 16));
        }
    }
    __syncthreads();
    unsigned* Wrow = (unsigned*)(W + (size_t)row * K_DIM);  // 4096 dwords
    #pragma unroll
    for (int i = 0; i < K_DIM / 2 / 256; ++i) {
        int j = i * 256 + tid;
        unsigned pa = f32_to_bf16_rne(rowbuf[2 * j]);
        unsigned pb = f32_to_bf16_rne(rowbuf[2 * j + 1]);
        Wrow[j] = pa | (pb << 16);
    }
}

// ---------------- zero d_out fallback (ws too small diagnostic) ----------------
__global__ void zero_out_kernel(float* __restrict__ p, int n) {
    int i = blockIdx.x * blockDim.x + threadIdx.x;
    int stride = gridDim.x * blockDim.x;
    for (; i < n; i += stride) p[i] = 0.f;
}

// ---------------- bf16 NT GEMM, 256x256 8-phase (T2+T3+T4+T5) ----------------
// EXACT r6 schedule (measured 425-440 us, ~1280 TF, MfmaUtil 56-57,
// conflicts 0).  Structural variants all regressed and are closed:
//   r4/r5 32x32x16 frags   -> intrinsic 4 cyc/b128 read penalty (485 us)
//   r7 full fragment hoist -> defeated per-phase counted waits (643 us)
//   r9 (ksub,mh) phases    -> added lgkm serialization points (460 us)
// C[M][N] = A[M][K] * B[N][K]^T.  BM=BN=256, BK=64, 8 waves (2M x 4N),
// per-wave output 128x64 (acc[8][4] f32x4).  LDS 128 KiB double-buffered.
// Per K-tile: 4 phases {ds_read subtile | stage 1 half-tile | barrier |
// lgkmcnt(0) | setprio(1) 16 MFMA setprio(0) | (boundary vmcnt) | barrier};
// vmcnt(4) only at tile boundaries.  Staging liveness:
//   q0: A(t+1) h0 -> db^1   q1: A(t+1) h1 -> db^1
//   q2: B(t+2) h0 -> db     q3: B(t+2) h1 -> db   (B[db] dead after q0)
// LDS swizzle (T2, rule #21): slot (row,c) holds global k-chunk c^(row&7);
// staging pre-swizzles the global source, reads apply the same involution.
__global__ __launch_bounds__(512, 2) void gemm_bt(const ushort* __restrict__ A,
                                                  const ushort* __restrict__ B,
                                                  float* __restrict__ C) {
    constexpr int BK = 64;
    constexpr int NT = K_DIM / BK;     // 128 K-tiles
    __shared__ ushort lds[65536];      // 128 KiB

    const int nbn = N_DIM / 256;       // 32
    const int bm = blockIdx.x / nbn;
    const int bn = blockIdx.x % nbn;
    const int brow = bm * 256, bcol = bn * 256;

    const int t    = threadIdx.x;
    const int lane = t & 63;
    const int wid  = t >> 6;           // 0..7
    const int wm   = wid >> 2;         // 0..1 (M)
    const int wn   = wid & 3;          // 0..3 (N)
    const int lrow = lane & 15;
    const int ghi  = lane >> 4;        // 0..3

    const int c0 = (0 + ghi) ^ (lrow & 7);   // ksub 0
    const int c1 = (4 + ghi) ^ (lrow & 7);   // ksub 1

    f32x4  acc[8][4] = {};
    bf16x8 bfr[4][2];                  // B frags, live across one tile

    auto stage_half = [&](int db, int op, int half, int ktile) {
        const ushort* G = (op == 0) ? A : B;
        const int rbase = ((op == 0) ? brow : bcol) + half * 128;
        #pragma unroll
        for (int i = 0; i < 2; ++i) {
            int fl  = i * 512 + t;                 // 0..1023
            int row = fl >> 3;
            int cc  = (fl & 7) ^ (row & 7);
            const ushort* src = G + (size_t)(rbase + row) * K_DIM + ktile * BK + cc * 8;
            __builtin_amdgcn_global_load_lds(
                (const __attribute__((address_space(1))) void*)src,
                (__attribute__((address_space(3))) void*)
                    (&lds[db * 32768 + op * 16384 + half * 8192 + fl * 8]),
                16, 0, 0);
        }
    };

    auto tile_body = [&](int tt, int db, bool stgA, bool stgB, int vm) {
        const ushort* Ah = &lds[db * 32768 + wm * 8192];
        const ushort* Bh = &lds[db * 32768 + 16384 + (wn >> 1) * 8192 + (wn & 1) * 4096];
        const ushort* a0 = Ah + lrow * 64 + c0 * 8;
        const ushort* a1 = Ah + lrow * 64 + c1 * 8;
        const ushort* b0 = Bh + lrow * 64 + c0 * 8;
        const ushort* b1 = Bh + lrow * 64 + c1 * 8;
        #pragma unroll
        for (int q = 0; q < 4; ++q) {
            bf16x8 af[2][2];
            if (q == 0) {
                #pragma unroll
                for (int n = 0; n < 4; ++n) {
                    bfr[n][0] = *(const bf16x8*)(b0 + n * 1024);
                    bfr[n][1] = *(const bf16x8*)(b1 + n * 1024);
                }
            }
            #pragma unroll
            for (int j = 0; j < 2; ++j) {
                af[j][0] = *(const bf16x8*)(a0 + (2 * q + j) * 1024);
                af[j][1] = *(const bf16x8*)(a1 + (2 * q + j) * 1024);
            }
            if (q == 0 && stgA) stage_half(db ^ 1, 0, 0, tt + 1);
            if (q == 1 && stgA) stage_half(db ^ 1, 0, 1, tt + 1);
            if (q == 2 && stgB) stage_half(db,     1, 0, tt + 2);
            if (q == 3 && stgB) stage_half(db,     1, 1, tt + 2);
            __builtin_amdgcn_s_barrier();
            asm volatile("s_waitcnt lgkmcnt(0)" ::: "memory");
            __builtin_amdgcn_s_setprio(1);
            #pragma unroll
            for (int j = 0; j < 2; ++j)
                #pragma unroll
                for (int n = 0; n < 4; ++n) {
                    acc[2 * q + j][n] = __builtin_amdgcn_mfma_f32_16x16x32_bf16(
                        af[j][0], bfr[n][0], acc[2 * q + j][n], 0, 0, 0);
                    acc[2 * q + j][n] = __builtin_amdgcn_mfma_f32_16x16x32_bf16(
                        af[j][1], bfr[n][1], acc[2 * q + j][n], 0, 0, 0);
                }
            __builtin_amdgcn_s_setprio(0);
            if (q == 3) {
                if (vm == 4) asm volatile("s_waitcnt vmcnt(4)" ::: "memory");
                else         asm volatile("s_waitcnt vmcnt(0)" ::: "memory");
            }
            __builtin_amdgcn_s_barrier();
        }
    };

    // ---- prologue: tile 0 fully + B(1); drain to 4 (B(1) stays in flight) ----
    stage_half(0, 0, 0, 0);
    stage_half(0, 0, 1, 0);
    stage_half(0, 1, 0, 0);
    stage_half(0, 1, 1, 0);
    stage_half(1, 1, 0, 1);
    stage_half(1, 1, 1, 1);
    asm volatile("s_waitcnt vmcnt(4)" ::: "memory");
    __builtin_amdgcn_s_barrier();

    for (int tt = 0; tt < NT - 2; tt += 2) {
        tile_body(tt,     0, true, true, 4);
        tile_body(tt + 1, 1, true, true, 4);
    }
    tile_body(NT - 2, 0, true,  false, 0);
    tile_body(NT - 1, 1, false, false, 0);

    // ---- epilogue: C/D layout col=lane&15, row=(lane>>4)*4+r ----
    const int crow0 = brow + wm * 128;
    const int ccol0 = bcol + wn * 64;
    #pragma unroll
    for (int m = 0; m < 8; ++m) {
        #pragma unroll
        for (int n = 0; n < 4; ++n) {
            int col   = ccol0 + n * 16 + lrow;
            int rbase = crow0 + m * 16 + (lane >> 4) * 4;
            #pragma unroll
            for (int r = 0; r < 4; ++r)
                C[(size_t)(rbase + r) * N_DIM + col] = acc[m][n][r];
        }
    }
}

extern "C" void kernel_launch(void* const* d_in, const int* in_sizes, int n_in,
                              void* d_out, int out_size, void* d_ws, size_t ws_size,
                              hipStream_t stream) {
    const float* x    = (const float*)d_in[0];
    const float* vals = (const float*)d_in[1];
    const int* rows   = (const int*)d_in[2];
    const int* cols   = (const int*)d_in[3];
    float* out        = (float*)d_out;
    const int n_items = in_sizes[1];

    const size_t W_BF16_BYTES = (size_t)N_DIM * K_DIM * 2;        // 128 MiB
    const size_t X_BF16_BYTES = (size_t)M_DIM * K_DIM * 2;        //  64 MiB
    const size_t BINS_BYTES   = (size_t)N_DIM * CAP * 4;          //  24 MiB
    const size_t FILL_BYTES   = (size_t)N_DIM * 4;                //  32 KiB
    const size_t OVF_BYTES    = 16 + (size_t)OVF_CAP * 8;
    const size_t NEEDED = W_BF16_BYTES + X_BF16_BYTES + BINS_BYTES
                        + FILL_BYTES + OVF_BYTES;

    if (ws_size < NEEDED) {
        // Diagnostic fallback: clean absmax=126 failure signals ws too small.
        zero_out_kernel<<<2048, 256, 0, stream>>>(out, out_size);
        return;
    }

    char* ws = (char*)d_ws;
    unsigned short* Wb = (unsigned short*)ws;
    ushort*   Xb      = (ushort*)(ws + W_BF16_BYTES);
    unsigned* bins    = (unsigned*)(ws + W_BF16_BYTES + X_BF16_BYTES);
    unsigned* fill    = (unsigned*)(ws + W_BF16_BYTES + X_BF16_BYTES + BINS_BYTES);
    unsigned* ovf_cnt = fill + N_DIM;
    uint2*    ovf     = (uint2*)(ovf_cnt + 4);

    // 1) zero fill counters + ovf_cnt (stream memset: graph-capturable)
    hipMemsetAsync(fill, 0, FILL_BYTES + 16, stream);
    // 2) fused: cast x to bf16 (even bids) || bin items 4/thread (odd bids)
    const int reorder_blocks = (n_items / 4 + 255) / 256;   // 3907
    cvt_reorder_kernel<<<2 * reorder_blocks, 256, 0, stream>>>(
        (const float4*)x, (ushort4*)Xb, (M_DIM * K_DIM) / 4,
        vals, rows, cols, bins, fill, ovf_cnt, ovf, n_items);
    // 3) per-row accumulate in f32 LDS + merge overflow + write bf16 W
    row_accum_kernel<<<N_DIM, 256, 0, stream>>>(bins, fill, ovf_cnt, ovf, Wb);
    // 4) GEMM: out = Xb (M x K) * Wb (N x K)^T
    gemm_bt<<<(M_DIM / 256) * (N_DIM / 256), 512, 0, stream>>>(
        Xb, (const ushort*)Wb, out);
}